// Round 2
// baseline (1184.334 us; speedup 1.0000x reference)
//
#include <hip/hip_runtime.h>
#include <hip/hip_bf16.h>

#define DEV __device__ __forceinline__
typedef unsigned short u16;
using s16x8  = __attribute__((ext_vector_type(8))) short;
using f32x4v = __attribute__((ext_vector_type(4))) float;

constexpr float SCALE  = 0.0625f;   // 256^-0.5
constexpr float EPS    = 1e-8f;
constexpr float LN_EPS = 1e-5f;

DEV u16 f2bf(float f) {
    __hip_bfloat16 h = __float2bfloat16(f);
    u16 u; __builtin_memcpy(&u, &h, 2); return u;
}
DEV float bf2f(u16 u) {
    unsigned int x = ((unsigned int)u) << 16;
    float f; __builtin_memcpy(&f, &x, 4); return f;
}
// dtype-agnostic scalar load: bf=1 -> buffer holds bf16, else f32
DEV float ld1(const void* p, size_t i, int bf) {
    return bf ? bf2f(((const u16*)p)[i]) : ((const float*)p)[i];
}
DEV void ld8f(const void* x, size_t base, int bf, float* out) {
    if (bf) {
        s16x8 t = *(const s16x8*)((const u16*)x + base);
#pragma unroll
        for (int i = 0; i < 8; i++) out[i] = bf2f((u16)t[i]);
    } else {
        const float4* p = (const float4*)((const float*)x + base);
        float4 a = p[0], b = p[1];
        out[0]=a.x; out[1]=a.y; out[2]=a.z; out[3]=a.w;
        out[4]=b.x; out[5]=b.y; out[6]=b.z; out[7]=b.w;
    }
}
DEV s16x8 pack8(float4 a, float4 b) {
    s16x8 o;
    o[0]=(short)f2bf(a.x); o[1]=(short)f2bf(a.y); o[2]=(short)f2bf(a.z); o[3]=(short)f2bf(a.w);
    o[4]=(short)f2bf(b.x); o[5]=(short)f2bf(b.y); o[6]=(short)f2bf(b.z); o[7]=(short)f2bf(b.w);
    return o;
}
DEV float warp_sum64(float v) {
    v += __shfl_xor(v, 1);  v += __shfl_xor(v, 2);  v += __shfl_xor(v, 4);
    v += __shfl_xor(v, 8);  v += __shfl_xor(v, 16); v += __shfl_xor(v, 32);
    return v;
}

// ---------------- dtype sniffer: bf16 data -> all even shorts decode sane ----------------
__global__ void k_sniff(const void* __restrict__ x, int* __restrict__ flag) {
    int lane = threadIdx.x;                       // 64 threads
    u16 u = ((const u16*)x)[lane * 2];            // low halves if f32
    float v = bf2f(u);
    bool bad = !(fabsf(v) <= 1024.0f);            // catches NaN too
    unsigned long long m = __ballot(bad);
    if (lane == 0) *flag = (m == 0ull) ? 1 : 0;
}

// ---------------- small f32 vectors -> canonical f32 ws copies ----------------
__global__ __launch_bounds__(256) void k_prep_misc(
    const void* bq, const void* bk, const void* bv, const void* bih, const void* bhh,
    const void* b1, const void* b2, const void* liw, const void* lib,
    const void* lsw, const void* lsb, const void* lfw, const void* lfb,
    float* o_bq, float* o_bk, float* o_bv, float* o_bih, float* o_bhh,
    float* o_b1, float* o_b2, float* o_liw, float* o_lib,
    float* o_lsw, float* o_lsb, float* o_lfw, float* o_lfb,
    const int* flagp) {
    int bf = *flagp;
    int i = blockIdx.x * 256 + threadIdx.x;
    if (i < 256) { o_bq[i]  = ld1(bq,  i, bf); return; } i -= 256;
    if (i < 256) { o_bk[i]  = ld1(bk,  i, bf); return; } i -= 256;
    if (i < 256) { o_bv[i]  = ld1(bv,  i, bf); return; } i -= 256;
    if (i < 768) { o_bih[i] = ld1(bih, i, bf); return; } i -= 768;
    if (i < 768) { o_bhh[i] = ld1(bhh, i, bf); return; } i -= 768;
    if (i < 512) { o_b1[i]  = ld1(b1,  i, bf); return; } i -= 512;
    if (i < 256) { o_b2[i]  = ld1(b2,  i, bf); return; } i -= 256;
    if (i < 256) { o_liw[i] = ld1(liw, i, bf); return; } i -= 256;
    if (i < 256) { o_lib[i] = ld1(lib, i, bf); return; } i -= 256;
    if (i < 256) { o_lsw[i] = ld1(lsw, i, bf); return; } i -= 256;
    if (i < 256) { o_lsb[i] = ld1(lsb, i, bf); return; } i -= 256;
    if (i < 256) { o_lfw[i] = ld1(lfw, i, bf); return; } i -= 256;
    if (i < 256) { o_lfb[i] = ld1(lfb, i, bf); }
}

// ---------------- weights -> bf16 (+ wk2[c][d] = wk[d][c]*ln_in_w[c]) ----------------
__global__ __launch_bounds__(256) void k_prep_w(
    const void* wq, const void* wv, const void* wk,
    const void* wih, const void* whh, const void* w1, const void* w2,
    u16* wq_b, u16* wv_b, u16* wk2_b, u16* wih_b, u16* whh_b, u16* w1_b, u16* w2_b,
    const float* __restrict__ lnw_f, const int* flagp) {
    int bf = *flagp;
    int i = blockIdx.x * 256 + threadIdx.x;
    if (i < 65536)  { wq_b[i]  = f2bf(ld1(wq,  i, bf)); return; } i -= 65536;
    if (i < 65536)  { wv_b[i]  = f2bf(ld1(wv,  i, bf)); return; } i -= 65536;
    if (i < 196608) { wih_b[i] = f2bf(ld1(wih, i, bf)); return; } i -= 196608;
    if (i < 196608) { whh_b[i] = f2bf(ld1(whh, i, bf)); return; } i -= 196608;
    if (i < 131072) { w1_b[i]  = f2bf(ld1(w1,  i, bf)); return; } i -= 131072;
    if (i < 131072) { w2_b[i]  = f2bf(ld1(w2,  i, bf)); return; } i -= 131072;
    if (i < 65536)  {
        int c = i >> 8, d = i & 255;
        wk2_b[i] = f2bf(ld1(wk, (size_t)d * 256 + c, bf) * lnw_f[c]);
    }
}

// ---------------- m1[d] = sum_c wk[d][c]*ln_in_b[c] + bk[d]; m2[d] = -sum_c wk[d][c]*ln_in_w[c] ----------------
__global__ __launch_bounds__(256) void k_prep_m(const void* __restrict__ wk,
    const float* __restrict__ lnw_f, const float* __restrict__ lnb_f,
    const float* __restrict__ bk_f, float* __restrict__ m1p, float* __restrict__ m2p,
    const int* flagp) {
    int bf = *flagp;
    int wave = threadIdx.x >> 6, lane = threadIdx.x & 63;
    int d = blockIdx.x * 4 + wave;
    float s1 = 0.f, s2 = 0.f;
#pragma unroll
    for (int t = 0; t < 4; t++) {
        int c = lane * 4 + t;
        float w = ld1(wk, (size_t)d * 256 + c, bf);
        s1 += w * lnb_f[c];
        s2 += w * lnw_f[c];
    }
    s1 = warp_sum64(s1); s2 = warp_sum64(s2);
    if (lane == 0) { m1p[d] = s1 + bk_f[d]; m2p[d] = -s2; }
}

// ---------------- per-row LN stats of inputs (one wave per row) ----------------
__global__ __launch_bounds__(256) void k_stats(const void* __restrict__ x,
                                               float* __restrict__ mu,
                                               float* __restrict__ rs,
                                               const int* flagp) {
    int bf = *flagp;
    int wave = threadIdx.x >> 6, lane = threadIdx.x & 63;
    int row  = blockIdx.x * 4 + wave;
    float v[4];
    if (bf) {
        u16 a4[4];
        __builtin_memcpy(a4, (const u16*)x + (size_t)row * 256 + lane * 4, 8);
#pragma unroll
        for (int i = 0; i < 4; i++) v[i] = bf2f(a4[i]);
    } else {
        float4 f = *(const float4*)((const float*)x + (size_t)row * 256 + lane * 4);
        v[0]=f.x; v[1]=f.y; v[2]=f.z; v[3]=f.w;
    }
    float s  = v[0]+v[1]+v[2]+v[3];
    float s2 = v[0]*v[0]+v[1]*v[1]+v[2]*v[2]+v[3]*v[3];
    s = warp_sum64(s); s2 = warp_sum64(s2);
    if (lane == 0) {
        float m = s * (1.f/256.f);
        mu[row] = m;
        rs[row] = rsqrtf(s2 * (1.f/256.f) - m*m + LN_EPS);
    }
}

// ---------------- slots init + LN(slots) (block per row) ----------------
__global__ __launch_bounds__(256) void k_prep_s(const void* __restrict__ qp,
    const float* __restrict__ lnw, const float* __restrict__ lnb,
    float* __restrict__ slots, u16* __restrict__ slots_b, u16* __restrict__ s_b,
    const int* flagp) {
    int bf = *flagp;
    int m = blockIdx.x;           // b*8 + s
    int s_ = m & 7, d = threadIdx.x;
    float v = ld1(qp, (size_t)s_ * 256 + d, bf);
    slots[(size_t)m*256 + d]   = v;
    slots_b[(size_t)m*256 + d] = f2bf(v);
    __shared__ float red[8];
    float su = warp_sum64(v), sq = warp_sum64(v*v);
    int wave = threadIdx.x >> 6, lane = threadIdx.x & 63;
    if (lane == 0) { red[wave] = su; red[4+wave] = sq; }
    __syncthreads();
    float S1 = red[0]+red[1]+red[2]+red[3], S2 = red[4]+red[5]+red[6]+red[7];
    float muv = S1*(1.f/256.f);
    float rsv = rsqrtf(S2*(1.f/256.f) - muv*muv + LN_EPS);
    s_b[(size_t)m*256 + d] = f2bf((v - muv)*rsv*lnw[d] + lnb[d]);
}

// ---------------- LN-fused bf16 load of 8 normalized input elements ----------------
DEV s16x8 ln_load8(const void* __restrict__ x, int row, int koff, int bf,
                   const float* __restrict__ mu, const float* __restrict__ rs,
                   const float* __restrict__ lnw, const float* __restrict__ lnb) {
    float v[8];
    ld8f(x, (size_t)row * 256 + koff, bf, v);
    float m = mu[row], r = rs[row];
    s16x8 o;
#pragma unroll
    for (int i = 0; i < 8; i++)
        o[i] = (short)f2bf((v[i] - m) * r * lnw[koff + i] + lnb[koff + i]);
    return o;
}

// ---------------- v projection (transposed out): vT[b][d][j] = LN(x)[j,:].wv[d,:] + bv[d] ----------------
__global__ __launch_bounds__(256) void k_proj_v(
    const void* __restrict__ x, const float* __restrict__ mu, const float* __restrict__ rs,
    const float* __restrict__ lnw, const float* __restrict__ lnb,
    const u16* __restrict__ W, const float* __restrict__ bias,
    u16* __restrict__ out, const int* flagp) {
    int bf = *flagp;
    int n0 = blockIdx.x * 128;   // token rows j
    int m0 = blockIdx.y * 128;   // wv rows d
    int tid = threadIdx.x;
    int wave = tid >> 6, lane = tid & 63, quad = lane >> 4, l15 = lane & 15;
    int wm = wave >> 1, wn = wave & 1;
    __shared__ __attribute__((aligned(16))) u16 A_s[128*40];
    __shared__ __attribute__((aligned(16))) u16 B_s[128*40];
    f32x4v acc[4][4];
#pragma unroll
    for (int i = 0; i < 4; i++)
#pragma unroll
        for (int j = 0; j < 4; j++) acc[i][j] = (f32x4v){0.f,0.f,0.f,0.f};
    int r0 = tid >> 2, seg = tid & 3;
    for (int kc = 0; kc < 8; ++kc) {
        s16x8 a0 = *(const s16x8*)(W + (size_t)(m0 + r0     )*256 + kc*32 + seg*8);
        s16x8 a1 = *(const s16x8*)(W + (size_t)(m0 + r0 + 64)*256 + kc*32 + seg*8);
        s16x8 b0 = ln_load8(x, n0 + r0,      kc*32 + seg*8, bf, mu, rs, lnw, lnb);
        s16x8 b1 = ln_load8(x, n0 + r0 + 64, kc*32 + seg*8, bf, mu, rs, lnw, lnb);
        __syncthreads();
        *(s16x8*)(A_s + r0*40 + seg*8)      = a0;
        *(s16x8*)(A_s + (r0+64)*40 + seg*8) = a1;
        *(s16x8*)(B_s + r0*40 + seg*8)      = b0;
        *(s16x8*)(B_s + (r0+64)*40 + seg*8) = b1;
        __syncthreads();
        s16x8 af[4], bf_[4];
#pragma unroll
        for (int t = 0; t < 4; t++) af[t]  = *(const s16x8*)(A_s + (wm*64 + t*16 + l15)*40 + quad*8);
#pragma unroll
        for (int t = 0; t < 4; t++) bf_[t] = *(const s16x8*)(B_s + (wn*64 + t*16 + l15)*40 + quad*8);
#pragma unroll
        for (int ti = 0; ti < 4; ti++)
#pragma unroll
            for (int tj = 0; tj < 4; tj++)
                acc[ti][tj] = __builtin_amdgcn_mfma_f32_16x16x32_bf16(af[ti], bf_[tj], acc[ti][tj], 0, 0, 0);
    }
#pragma unroll
    for (int tj = 0; tj < 4; tj++) {
        int jg = n0 + wn*64 + tj*16 + l15;
        int bb = jg >> 12, jl = jg & 4095;
#pragma unroll
        for (int ti = 0; ti < 4; ti++) {
            int dbase = m0 + wm*64 + ti*16 + quad*4;
#pragma unroll
            for (int r = 0; r < 4; r++) {
                int dd = dbase + r;
                out[((size_t)bb*256 + dd)*4096 + jl] = f2bf(acc[ti][tj][r] + bias[dd]);
            }
        }
    }
}

// ---------------- generic small GEMM: C[M,N] = A[M,K] . W[N,K]^T + bias ----------------
template<bool OUT_BF16, bool RELU>
__global__ __launch_bounds__(256) void k_gemm_bt(
    const u16* __restrict__ A, const u16* __restrict__ W,
    const float* __restrict__ bias, void* __restrict__ outp,
    int M, int Nn, int K) {
    int m0 = blockIdx.x * 128, n0 = blockIdx.y * 128;
    int tid = threadIdx.x;
    int wave = tid >> 6, lane = tid & 63, quad = lane >> 4, l15 = lane & 15;
    int wm = wave >> 1, wn = wave & 1;
    __shared__ __attribute__((aligned(16))) u16 A_s[128*40];
    __shared__ __attribute__((aligned(16))) u16 B_s[128*40];
    f32x4v acc[4][4];
#pragma unroll
    for (int i = 0; i < 4; i++)
#pragma unroll
        for (int j = 0; j < 4; j++) acc[i][j] = (f32x4v){0.f,0.f,0.f,0.f};
    int r0 = tid >> 2, seg = tid & 3;
    int nkc = K >> 5;
    for (int kc = 0; kc < nkc; ++kc) {
        s16x8 a0 = *(const s16x8*)(A + (size_t)(m0 + r0     )*K + kc*32 + seg*8);
        s16x8 a1 = *(const s16x8*)(A + (size_t)(m0 + r0 + 64)*K + kc*32 + seg*8);
        s16x8 b0 = *(const s16x8*)(W + (size_t)(n0 + r0     )*K + kc*32 + seg*8);
        s16x8 b1 = *(const s16x8*)(W + (size_t)(n0 + r0 + 64)*K + kc*32 + seg*8);
        __syncthreads();
        *(s16x8*)(A_s + r0*40 + seg*8)      = a0;
        *(s16x8*)(A_s + (r0+64)*40 + seg*8) = a1;
        *(s16x8*)(B_s + r0*40 + seg*8)      = b0;
        *(s16x8*)(B_s + (r0+64)*40 + seg*8) = b1;
        __syncthreads();
        s16x8 af[4], bf_[4];
#pragma unroll
        for (int t = 0; t < 4; t++) af[t]  = *(const s16x8*)(A_s + (wm*64 + t*16 + l15)*40 + quad*8);
#pragma unroll
        for (int t = 0; t < 4; t++) bf_[t] = *(const s16x8*)(B_s + (wn*64 + t*16 + l15)*40 + quad*8);
#pragma unroll
        for (int ti = 0; ti < 4; ti++)
#pragma unroll
            for (int tj = 0; tj < 4; tj++)
                acc[ti][tj] = __builtin_amdgcn_mfma_f32_16x16x32_bf16(af[ti], bf_[tj], acc[ti][tj], 0, 0, 0);
    }
#pragma unroll
    for (int tj = 0; tj < 4; tj++) {
        int colg = n0 + wn*64 + tj*16 + l15;
        float bv_ = bias ? bias[colg] : 0.f;
#pragma unroll
        for (int ti = 0; ti < 4; ti++) {
            int rowb = m0 + wm*64 + ti*16 + quad*4;
#pragma unroll
            for (int r = 0; r < 4; r++) {
                float v = acc[ti][tj][r] + bv_;
                if (RELU) v = fmaxf(v, 0.f);
                if (OUT_BF16) ((u16*)outp)[(size_t)(rowb + r)*Nn + colg] = f2bf(v);
                else          ((float*)outp)[(size_t)(rowb + r)*Nn + colg] = v;
            }
        }
    }
}

// ---------------- kappa/lambda per (b,i): kap = q.m1, lam = q.m2 ----------------
__global__ __launch_bounds__(256) void k_kl(const u16* __restrict__ qb,
    const float* __restrict__ m1p, const float* __restrict__ m2p,
    float* __restrict__ kap, float* __restrict__ lam) {
    int m = blockIdx.x, d = threadIdx.x;
    float qv = bf2f(qb[(size_t)m*256 + d]);
    float s1 = qv * m1p[d], s2 = qv * m2p[d];
    __shared__ float red[16];
    s1 = warp_sum64(s1); s2 = warp_sum64(s2);
    int wave = threadIdx.x >> 6, lane = threadIdx.x & 63;
    if (lane == 0) { red[wave] = s1; red[8+wave] = s2; }
    __syncthreads();
    if (threadIdx.x == 0) {
        kap[m] = red[0]+red[1]+red[2]+red[3];
        lam[m] = red[8]+red[9]+red[10]+red[11];
    }
}

// ---------------- fused attention: dots(from raw x) -> softmax(i)+EPS -> partial U,R ----------------
// dots[i][j] = SCALE*( rs_j*(q2[i].x_raw[j]) + mu_j*rs_j*lam[i] + kap[i] )
__global__ __launch_bounds__(256) void k_attn(
    const void* __restrict__ xraw, const u16* __restrict__ vTb,
    const u16* __restrict__ q2b, const float* __restrict__ kap,
    const float* __restrict__ lam, const float* __restrict__ mu,
    const float* __restrict__ rs, const int* __restrict__ flagp,
    float* __restrict__ Up, float* __restrict__ Rp) {
    int bf = *flagp;
    int jc = blockIdx.x;   // 0..15 (256 j each)
    int b  = blockIdx.y;   // 0..63
    int tid = threadIdx.x;
    int wave = tid >> 6, lane = tid & 63, quad = lane >> 4, l15 = lane & 15;
    __shared__ __attribute__((aligned(16))) u16 q_s[16*264];
    __shared__ __attribute__((aligned(16))) u16 a_s[16*264];
    __shared__ __attribute__((aligned(16))) u16 kv_s[256*40];
    __shared__ float kl_s[32];   // [0..15]=kappa, [16..31]=lambda (rows 8..15 zero)
    {   // stage q2 (rows 0..7 real, 8..15 zero)
        int row = tid >> 5, seg = tid & 31;
        s16x8 qv = *(const s16x8*)(q2b + (size_t)(b*8 + row)*256 + seg*8);
        *(s16x8*)(q_s + row*264 + seg*8) = qv;
        s16x8 z = {0,0,0,0,0,0,0,0};
        *(s16x8*)(q_s + (8+row)*264 + seg*8) = z;
    }
    if (tid < 16) {
        kl_s[tid]      = (tid < 8) ? kap[b*8 + tid] : 0.f;
        kl_s[16 + tid] = (tid < 8) ? lam[b*8 + tid] : 0.f;
    }
    f32x4v accd[4];
#pragma unroll
    for (int t = 0; t < 4; t++) accd[t] = (f32x4v){0.f,0.f,0.f,0.f};
    int jb = (b << 12) + (jc << 8);
    // ---- raw-x dot pass ----
    for (int kc = 0; kc < 8; ++kc) {
        s16x8 t0, t1, t2, t3;
        if (bf) {
            const s16x8* src = (const s16x8*)((const u16*)xraw + (size_t)(jb + tid)*256 + kc*32);
            t0 = src[0]; t1 = src[1]; t2 = src[2]; t3 = src[3];
        } else {
            const float4* sf = (const float4*)((const float*)xraw + (size_t)(jb + tid)*256 + kc*32);
            float4 f0=sf[0], f1=sf[1], f2=sf[2], f3=sf[3], f4=sf[4], f5=sf[5], f6=sf[6], f7=sf[7];
            t0 = pack8(f0,f1); t1 = pack8(f2,f3); t2 = pack8(f4,f5); t3 = pack8(f6,f7);
        }
        __syncthreads();
        *(s16x8*)(kv_s + tid*40 +  0) = t0;
        *(s16x8*)(kv_s + tid*40 +  8) = t1;
        *(s16x8*)(kv_s + tid*40 + 16) = t2;
        *(s16x8*)(kv_s + tid*40 + 24) = t3;
        __syncthreads();
        s16x8 af = *(const s16x8*)(q_s + l15*264 + kc*32 + quad*8);
#pragma unroll
        for (int tj = 0; tj < 4; tj++) {
            s16x8 bfv = *(const s16x8*)(kv_s + (wave*64 + tj*16 + l15)*40 + quad*8);
            accd[tj] = __builtin_amdgcn_mfma_f32_16x16x32_bf16(af, bfv, accd[tj], 0, 0, 0);
        }
    }
    // ---- affine fixup, softmax over i (lane <-> lane^16), +EPS, stash a, partial R ----
    float racc[4] = {0.f, 0.f, 0.f, 0.f};
#pragma unroll
    for (int tj = 0; tj < 4; tj++) {
        int col = wave*64 + tj*16 + l15;
        int jg = jb + col;
        float rsj = rs[jg], mrj = mu[jg] * rsj;
        float d0 = SCALE*(rsj*accd[tj][0] + mrj*kl_s[16+quad*4+0] + kl_s[quad*4+0]);
        float d1 = SCALE*(rsj*accd[tj][1] + mrj*kl_s[16+quad*4+1] + kl_s[quad*4+1]);
        float d2 = SCALE*(rsj*accd[tj][2] + mrj*kl_s[16+quad*4+2] + kl_s[quad*4+2]);
        float d3 = SCALE*(rsj*accd[tj][3] + mrj*kl_s[16+quad*4+3] + kl_s[quad*4+3]);
        float mx = fmaxf(fmaxf(d0, d1), fmaxf(d2, d3));
        mx = fmaxf(mx, __shfl_xor(mx, 16));
        float e0 = expf(d0-mx), e1 = expf(d1-mx), e2 = expf(d2-mx), e3 = expf(d3-mx);
        float sum = e0+e1+e2+e3;
        sum += __shfl_xor(sum, 16);
        float inv = 1.f / sum;
        float a0 = e0*inv + EPS, a1 = e1*inv + EPS, a2 = e2*inv + EPS, a3 = e3*inv + EPS;
        a_s[(quad*4+0)*264 + col] = f2bf(a0);
        a_s[(quad*4+1)*264 + col] = f2bf(a1);
        a_s[(quad*4+2)*264 + col] = f2bf(a2);
        a_s[(quad*4+3)*264 + col] = f2bf(a3);
        racc[0] += a0; racc[1] += a1; racc[2] += a2; racc[3] += a3;
    }
#pragma unroll
    for (int r = 0; r < 4; r++) {
        racc[r] += __shfl_xor(racc[r], 1);
        racc[r] += __shfl_xor(racc[r], 2);
        racc[r] += __shfl_xor(racc[r], 4);
        racc[r] += __shfl_xor(racc[r], 8);
    }
    if (l15 == 0 && quad < 2) {
        int base = ((b*16 + jc)*4 + wave)*8 + quad*4;
        Rp[base+0] = racc[0]; Rp[base+1] = racc[1];
        Rp[base+2] = racc[2]; Rp[base+3] = racc[3];
    }
    __syncthreads();   // a_s complete
    // ---- partial U = a . v  (K = the block's 256 j) ----
    f32x4v accu[4];
#pragma unroll
    for (int t = 0; t < 4; t++) accu[t] = (f32x4v){0.f,0.f,0.f,0.f};
    for (int kc = 0; kc < 8; ++kc) {
        const s16x8* src = (const s16x8*)(vTb + ((size_t)(b*256 + tid))*4096 + (jc << 8) + kc*32);
        s16x8 t0 = src[0], t1 = src[1], t2 = src[2], t3 = src[3];
        __syncthreads();
        *(s16x8*)(kv_s + tid*40 +  0) = t0;
        *(s16x8*)(kv_s + tid*40 +  8) = t1;
        *(s16x8*)(kv_s + tid*40 + 16) = t2;
        *(s16x8*)(kv_s + tid*40 + 24) = t3;
        __syncthreads();
        s16x8 af = *(const s16x8*)(a_s + l15*264 + kc*32 + quad*8);
#pragma unroll
        for (int tj = 0; tj < 4; tj++) {
            s16x8 bfv = *(const s16x8*)(kv_s + (wave*64 + tj*16 + l15)*40 + quad*8);
            accu[tj] = __builtin_amdgcn_mfma_f32_16x16x32_bf16(af, bfv, accu[tj], 0, 0, 0);
        }
    }
    if (quad < 2) {
#pragma unroll
        for (int tj = 0; tj < 4; tj++) {
            int d = wave*64 + tj*16 + l15;
#pragma unroll
            for (int r = 0; r < 4; r++)
                Up[((size_t)(b*16 + jc)*8 + quad*4 + r)*256 + d] = accu[tj][r];
        }
    }
}

// ---------------- reduce partial U/R, divide, emit bf16 updates ----------------
__global__ __launch_bounds__(256) void k_reduce_u(const float* __restrict__ Up,
    const float* __restrict__ Rp, u16* __restrict__ upd_b) {
    int m = blockIdx.x;  // b*8 + i
    int b = m >> 3, i = m & 7, d = threadIdx.x;
    float u = 0.f;
#pragma unroll
    for (int c = 0; c < 16; c++) u += Up[((size_t)(b*16 + c)*8 + i)*256 + d];
    float R = 0.f;
    for (int p = 0; p < 64; p++) R += Rp[(size_t)(b*64 + p)*8 + i];
    upd_b[(size_t)m*256 + d] = f2bf(u / R);
}

// ---------------- GRU gates + h + LN_ff(h) ----------------
__global__ __launch_bounds__(256) void k_gates(const float* __restrict__ gx,
    const float* __restrict__ gh, const float* __restrict__ slots,
    const float* __restrict__ lnw, const float* __restrict__ lnb,
    float* __restrict__ h, u16* __restrict__ hln_b) {
    int m = blockIdx.x, d = threadIdx.x;
    size_t o3 = (size_t)m*768 + d;
    float xr = gx[o3], xz = gx[o3+256], xn = gx[o3+512];
    float hr = gh[o3], hz = gh[o3+256], hn = gh[o3+512];
    float r = 1.f/(1.f + expf(-(xr+hr)));
    float z = 1.f/(1.f + expf(-(xz+hz)));
    float n = tanhf(xn + r*hn);
    float hv = (1.f - z)*n + z*slots[(size_t)m*256 + d];
    h[(size_t)m*256 + d] = hv;
    __shared__ float red[8];
    float su = warp_sum64(hv), sq = warp_sum64(hv*hv);
    int wave = threadIdx.x >> 6, lane = threadIdx.x & 63;
    if (lane == 0) { red[wave] = su; red[4+wave] = sq; }
    __syncthreads();
    float S1 = red[0]+red[1]+red[2]+red[3], S2 = red[4]+red[5]+red[6]+red[7];
    float muv = S1*(1.f/256.f);
    float rsv = rsqrtf(S2*(1.f/256.f) - muv*muv + LN_EPS);
    hln_b[(size_t)m*256 + d] = f2bf((hv - muv)*rsv*lnw[d] + lnb[d]);
}

// ---------------- residual + next-step LN(slots) ----------------
__global__ __launch_bounds__(256) void k_residual(const float* __restrict__ h,
    const float* __restrict__ ff2, const float* __restrict__ lnw,
    const float* __restrict__ lnb, float* __restrict__ slots,
    u16* __restrict__ slots_b, u16* __restrict__ s_b) {
    int m = blockIdx.x, d = threadIdx.x;
    float sv = h[(size_t)m*256 + d] + ff2[(size_t)m*256 + d];
    slots[(size_t)m*256 + d]   = sv;
    slots_b[(size_t)m*256 + d] = f2bf(sv);
    __shared__ float red[8];
    float su = warp_sum64(sv), sq = warp_sum64(sv*sv);
    int wave = threadIdx.x >> 6, lane = threadIdx.x & 63;
    if (lane == 0) { red[wave] = su; red[4+wave] = sq; }
    __syncthreads();
    float S1 = red[0]+red[1]+red[2]+red[3], S2 = red[4]+red[5]+red[6]+red[7];
    float muv = S1*(1.f/256.f);
    float rsv = rsqrtf(S2*(1.f/256.f) - muv*muv + LN_EPS);
    s_b[(size_t)m*256 + d] = f2bf((sv - muv)*rsv*lnw[d] + lnb[d]);
}

// ---------------- final output (dtype matches regime) ----------------
__global__ __launch_bounds__(256) void k_out(const float* __restrict__ slots,
                                             void* __restrict__ out, const int* flagp) {
    int bf = *flagp;
    int i = blockIdx.x * 256 + threadIdx.x;
    if (bf) ((u16*)out)[i] = f2bf(slots[i]);
    else    ((float*)out)[i] = slots[i];
}

extern "C" void kernel_launch(void* const* d_in, const int* in_sizes, int n_in,
                              void* d_out, int out_size, void* d_ws, size_t ws_size,
                              hipStream_t stream) {
    (void)in_sizes; (void)n_in; (void)out_size; (void)ws_size;
    const void* inputs    = d_in[0];
    const void* query_pos = d_in[1];
    const void* wq   = d_in[2];
    const void* bq   = d_in[3];
    const void* wk   = d_in[4];
    const void* bk   = d_in[5];
    const void* wv   = d_in[6];
    const void* bv   = d_in[7];
    const void* w_ih = d_in[8];
    const void* b_ih = d_in[9];
    const void* w_hh = d_in[10];
    const void* b_hh = d_in[11];
    const void* w1   = d_in[12];
    const void* b1   = d_in[13];
    const void* w2   = d_in[14];
    const void* b2   = d_in[15];
    const void* ln_in_w = d_in[16];
    const void* ln_in_b = d_in[17];
    const void* ln_s_w  = d_in[18];
    const void* ln_s_b  = d_in[19];
    const void* ln_ff_w = d_in[20];
    const void* ln_ff_b = d_in[21];

    char* w = (char*)d_ws;
    size_t off = 0;
    auto alloc = [&](size_t bytes) -> void* {
        void* p = w + off;
        off = (off + bytes + 255) & ~(size_t)255;
        return p;
    };
    u16*   vT_b   = (u16*)alloc(134217728);   // [B][256][4096] bf16
    u16*   wq_b   = (u16*)alloc(131072);
    u16*   wv_b   = (u16*)alloc(131072);
    u16*   wk2_b  = (u16*)alloc(131072);
    u16*   wih_b  = (u16*)alloc(393216);
    u16*   whh_b  = (u16*)alloc(393216);
    u16*   w1_b   = (u16*)alloc(262144);
    u16*   w2_b   = (u16*)alloc(262144);
    float* bq_f   = (float*)alloc(1024);
    float* bk_f   = (float*)alloc(1024);
    float* bv_f   = (float*)alloc(1024);
    float* bih_f  = (float*)alloc(3072);
    float* bhh_f  = (float*)alloc(3072);
    float* b1_f   = (float*)alloc(2048);
    float* b2_f   = (float*)alloc(1024);
    float* liw_f  = (float*)alloc(1024);
    float* lib_f  = (float*)alloc(1024);
    float* lsw_f  = (float*)alloc(1024);
    float* lsb_f  = (float*)alloc(1024);
    float* lfw_f  = (float*)alloc(1024);
    float* lfb_f  = (float*)alloc(1024);
    float* m1p    = (float*)alloc(1024);
    float* m2p    = (float*)alloc(1024);
    int*   flag   = (int*)alloc(256);
    float* mu     = (float*)alloc(1048576);
    float* rs     = (float*)alloc(1048576);
    float* slots  = (float*)alloc(524288);
    u16*   slots_b= (u16*)alloc(262144);
    u16*   s_b    = (u16*)alloc(262144);
    u16*   q_b    = (u16*)alloc(262144);
    u16*   q2_b   = (u16*)alloc(262144);
    float* kap    = (float*)alloc(2048);
    float* lam    = (float*)alloc(2048);
    float* Rp     = (float*)alloc(131072);    // [B][64][8]
    u16*   upd_b  = (u16*)alloc(262144);
    // step temporaries alias the Up buffer (disjoint lifetimes within a step)
    char*  uni    = (char*)alloc(8388608);
    float* Up     = (float*)uni;              // [B][16][8][256] f32
    float* gx     = (float*)uni;
    float* gh     = (float*)(uni + 1572864);
    float* h      = (float*)(uni + 3145728);
    u16*   hln_b  = (u16*)  (uni + 3670016);
    u16*   ff1_b  = (u16*)  (uni + 3932160);
    float* ff2    = (float*)(uni + 4456448);

    k_sniff<<<1, 64, 0, stream>>>(inputs, flag);
    k_prep_misc<<<18, 256, 0, stream>>>(bq, bk, bv, b_ih, b_hh, b1, b2,
                                        ln_in_w, ln_in_b, ln_s_w, ln_s_b, ln_ff_w, ln_ff_b,
                                        bq_f, bk_f, bv_f, bih_f, bhh_f, b1_f, b2_f,
                                        liw_f, lib_f, lsw_f, lsb_f, lfw_f, lfb_f, flag);
    k_prep_w<<<3328, 256, 0, stream>>>(wq, wv, wk, w_ih, w_hh, w1, w2,
                                       wq_b, wv_b, wk2_b, wih_b, whh_b, w1_b, w2_b,
                                       liw_f, flag);
    k_prep_m<<<64, 256, 0, stream>>>(wk, liw_f, lib_f, bk_f, m1p, m2p, flag);
    k_prep_s<<<512, 256, 0, stream>>>(query_pos, lsw_f, lsb_f, slots, slots_b, s_b, flag);
    k_stats<<<65536, 256, 0, stream>>>(inputs, mu, rs, flag);
    k_proj_v<<<dim3(2048, 2), 256, 0, stream>>>(inputs, mu, rs, liw_f, lib_f, wv_b, bv_f, vT_b, flag);

    for (int step = 0; step < 4; ++step) {
        k_gemm_bt<true,  false><<<dim3(4, 2), 256, 0, stream>>>(s_b,   wq_b,  bq_f, q_b,  512, 256, 256);
        k_gemm_bt<true,  false><<<dim3(4, 2), 256, 0, stream>>>(q_b,   wk2_b, nullptr, q2_b, 512, 256, 256);
        k_kl<<<512, 256, 0, stream>>>(q_b, m1p, m2p, kap, lam);
        k_attn<<<dim3(16, 64), 256, 0, stream>>>(inputs, vT_b, q2_b, kap, lam, mu, rs, flag, Up, Rp);
        k_reduce_u<<<512, 256, 0, stream>>>(Up, Rp, upd_b);
        k_gemm_bt<false, false><<<dim3(4, 6), 256, 0, stream>>>(upd_b,   wih_b, bih_f, gx,  512, 768, 256);
        k_gemm_bt<false, false><<<dim3(4, 6), 256, 0, stream>>>(slots_b, whh_b, bhh_f, gh,  512, 768, 256);
        k_gates<<<512, 256, 0, stream>>>(gx, gh, slots, lfw_f, lfb_f, h, hln_b);
        k_gemm_bt<true,  true ><<<dim3(4, 4), 256, 0, stream>>>(hln_b, w1_b, b1_f, ff1_b, 512, 512, 256);
        k_gemm_bt<false, false><<<dim3(4, 2), 256, 0, stream>>>(ff1_b, w2_b, b2_f, ff2,   512, 256, 512);
        k_residual<<<512, 256, 0, stream>>>(h, ff2, lsw_f, lsb_f, slots, slots_b, s_b);
    }
    k_out<<<512, 256, 0, stream>>>(slots, d_out, flag);
}

// Round 3
// 808.974 us; speedup vs baseline: 1.4640x; 1.4640x over previous
//
#include <hip/hip_runtime.h>
#include <hip/hip_bf16.h>

#define DEV __device__ __forceinline__
typedef unsigned short u16;
using s16x8  = __attribute__((ext_vector_type(8))) short;
using f32x4v = __attribute__((ext_vector_type(4))) float;

constexpr float SCALE  = 0.0625f;   // 256^-0.5
constexpr float EPS    = 1e-8f;
constexpr float LN_EPS = 1e-5f;

DEV u16 f2bf(float f) {
    __hip_bfloat16 h = __float2bfloat16(f);
    u16 u; __builtin_memcpy(&u, &h, 2); return u;
}
DEV float bf2f(u16 u) {
    unsigned int x = ((unsigned int)u) << 16;
    float f; __builtin_memcpy(&f, &x, 4); return f;
}
DEV float ld1(const void* p, size_t i, int bf) {
    return bf ? bf2f(((const u16*)p)[i]) : ((const float*)p)[i];
}
DEV s16x8 pack8(float4 a, float4 b) {
    s16x8 o;
    o[0]=(short)f2bf(a.x); o[1]=(short)f2bf(a.y); o[2]=(short)f2bf(a.z); o[3]=(short)f2bf(a.w);
    o[4]=(short)f2bf(b.x); o[5]=(short)f2bf(b.y); o[6]=(short)f2bf(b.z); o[7]=(short)f2bf(b.w);
    return o;
}
DEV float warp_sum64(float v) {
    v += __shfl_xor(v, 1);  v += __shfl_xor(v, 2);  v += __shfl_xor(v, 4);
    v += __shfl_xor(v, 8);  v += __shfl_xor(v, 16); v += __shfl_xor(v, 32);
    return v;
}
DEV float sigf(float x) { return 1.f / (1.f + expf(-x)); }

// ---------------- dtype sniffer ----------------
__global__ void k_sniff(const void* __restrict__ x, int* __restrict__ flag) {
    int lane = threadIdx.x;
    u16 u = ((const u16*)x)[lane * 2];
    float v = bf2f(u);
    bool bad = !(fabsf(v) <= 1024.0f);
    unsigned long long m = __ballot(bad);
    if (lane == 0) *flag = (m == 0ull) ? 1 : 0;
}

// ---------------- small vectors -> canonical f32 ----------------
__global__ __launch_bounds__(256) void k_prep_misc(
    const void* bq, const void* bk, const void* bv, const void* bih, const void* bhh,
    const void* b1, const void* b2, const void* liw, const void* lib,
    const void* lsw, const void* lsb, const void* lfw, const void* lfb,
    float* o_bq, float* o_bk, float* o_bv, float* o_bih, float* o_bhh,
    float* o_b1, float* o_b2, float* o_liw, float* o_lib,
    float* o_lsw, float* o_lsb, float* o_lfw, float* o_lfb,
    const int* flagp) {
    int bf = *flagp;
    int i = blockIdx.x * 256 + threadIdx.x;
    if (i < 256) { o_bq[i]  = ld1(bq,  i, bf); return; } i -= 256;
    if (i < 256) { o_bk[i]  = ld1(bk,  i, bf); return; } i -= 256;
    if (i < 256) { o_bv[i]  = ld1(bv,  i, bf); return; } i -= 256;
    if (i < 768) { o_bih[i] = ld1(bih, i, bf); return; } i -= 768;
    if (i < 768) { o_bhh[i] = ld1(bhh, i, bf); return; } i -= 768;
    if (i < 512) { o_b1[i]  = ld1(b1,  i, bf); return; } i -= 512;
    if (i < 256) { o_b2[i]  = ld1(b2,  i, bf); return; } i -= 256;
    if (i < 256) { o_liw[i] = ld1(liw, i, bf); return; } i -= 256;
    if (i < 256) { o_lib[i] = ld1(lib, i, bf); return; } i -= 256;
    if (i < 256) { o_lsw[i] = ld1(lsw, i, bf); return; } i -= 256;
    if (i < 256) { o_lsb[i] = ld1(lsb, i, bf); return; } i -= 256;
    if (i < 256) { o_lfw[i] = ld1(lfw, i, bf); return; } i -= 256;
    if (i < 256) { o_lfb[i] = ld1(lfb, i, bf); }
}

// ---------------- weights -> bf16 (wqT, wvT transposed; wk2[n][d]=wk[d][n]*liw[n]) ----------------
__global__ __launch_bounds__(256) void k_prep_w(
    const void* wq, const void* wv, const void* wk,
    const void* wih, const void* whh, const void* w1, const void* w2,
    u16* wqT_b, u16* wvT_b, u16* wk2_b, u16* wih_b, u16* whh_b, u16* w1_b, u16* w2_b,
    const float* __restrict__ liw, const int* flagp) {
    int bf = *flagp;
    int i = blockIdx.x * 256 + threadIdx.x;
    if (i < 65536)  { int c=i>>8, d=i&255; wqT_b[i] = f2bf(ld1(wq, (size_t)d*256+c, bf)); return; } i -= 65536;
    if (i < 65536)  { int c=i>>8, d=i&255; wvT_b[i] = f2bf(ld1(wv, (size_t)d*256+c, bf)); return; } i -= 65536;
    if (i < 65536)  { int n=i>>8, d=i&255; wk2_b[i] = f2bf(ld1(wk, (size_t)d*256+n, bf) * liw[n]); return; } i -= 65536;
    if (i < 196608) { wih_b[i] = f2bf(ld1(wih, i, bf)); return; } i -= 196608;
    if (i < 196608) { whh_b[i] = f2bf(ld1(whh, i, bf)); return; } i -= 196608;
    if (i < 131072) { w1_b[i]  = f2bf(ld1(w1,  i, bf)); return; } i -= 131072;
    if (i < 131072) { w2_b[i]  = f2bf(ld1(w2,  i, bf)); }
}

// ---------------- m1[d]=sum_c wk[d][c]*lib[c] + bk[d]; m2[d]=-sum_c wk[d][c]*liw[c] ----------------
__global__ __launch_bounds__(256) void k_prep_m(const void* __restrict__ wk,
    const float* __restrict__ liw, const float* __restrict__ lib,
    const float* __restrict__ bk_f, float* __restrict__ m1p, float* __restrict__ m2p,
    const int* flagp) {
    int bf = *flagp;
    int wave = threadIdx.x >> 6, lane = threadIdx.x & 63;
    int d = blockIdx.x * 4 + wave;
    float s1 = 0.f, s2 = 0.f;
#pragma unroll
    for (int t = 0; t < 4; t++) {
        int c = lane * 4 + t;
        float w = ld1(wk, (size_t)d * 256 + c, bf);
        s1 += w * lib[c];
        s2 += w * liw[c];
    }
    s1 = warp_sum64(s1); s2 = warp_sum64(s2);
    if (lane == 0) { m1p[d] = s1 + bk_f[d]; m2p[d] = -s2; }
}

// ---------------- u1[c]=sum_d wq[d,c]m1[d]; u2; bq2[n]=liw[n]*sum_d bq[d]wk[d,n]; wibv[n]=sum_d wih[n,d]bv[d]; c12 ----------------
__global__ __launch_bounds__(256) void k_prep_u(
    const void* __restrict__ wq, const void* __restrict__ wk, const void* __restrict__ wih,
    const float* __restrict__ m1p, const float* __restrict__ m2p,
    const float* __restrict__ bq_f, const float* __restrict__ bv_f,
    const float* __restrict__ liw,
    float* __restrict__ u1, float* __restrict__ u2, float* __restrict__ bq2,
    float* __restrict__ wibv, float* __restrict__ c12, const int* flagp) {
    int bf = *flagp;
    int wave = threadIdx.x >> 6, lane = threadIdx.x & 63;
    int idx = blockIdx.x * 4 + wave;
    if (idx >= 1538) return;
    float s = 0.f;
#pragma unroll
    for (int t = 0; t < 4; t++) {
        int d = lane * 4 + t;
        if (idx < 256)       s += ld1(wq, (size_t)d*256 + idx, bf) * m1p[d];
        else if (idx < 512)  s += ld1(wq, (size_t)d*256 + (idx-256), bf) * m2p[d];
        else if (idx < 768)  s += bq_f[d] * ld1(wk, (size_t)d*256 + (idx-512), bf);
        else if (idx < 1536) s += ld1(wih, (size_t)(idx-768)*256 + d, bf) * bv_f[d];
        else if (idx == 1536) s += bq_f[d] * m1p[d];
        else                  s += bq_f[d] * m2p[d];
    }
    s = warp_sum64(s);
    if (lane == 0) {
        if (idx < 256)       u1[idx] = s;
        else if (idx < 512)  u2[idx-256] = s;
        else if (idx < 768)  bq2[idx-512] = s * liw[idx-512];
        else if (idx < 1536) wibv[idx-768] = s;
        else                 c12[idx-1536] = s;
    }
}

// ---------------- per-row LN stats of inputs ----------------
__global__ __launch_bounds__(256) void k_stats(const void* __restrict__ x,
                                               float* __restrict__ mu,
                                               float* __restrict__ rs,
                                               const int* flagp) {
    int bf = *flagp;
    int wave = threadIdx.x >> 6, lane = threadIdx.x & 63;
    int row  = blockIdx.x * 4 + wave;
    float v[4];
    if (bf) {
        u16 a4[4];
        __builtin_memcpy(a4, (const u16*)x + (size_t)row * 256 + lane * 4, 8);
#pragma unroll
        for (int i = 0; i < 4; i++) v[i] = bf2f(a4[i]);
    } else {
        float4 f = *(const float4*)((const float*)x + (size_t)row * 256 + lane * 4);
        v[0]=f.x; v[1]=f.y; v[2]=f.z; v[3]=f.w;
    }
    float s  = v[0]+v[1]+v[2]+v[3];
    float s2 = v[0]*v[0]+v[1]*v[1]+v[2]*v[2]+v[3]*v[3];
    s = warp_sum64(s); s2 = warp_sum64(s2);
    if (lane == 0) {
        float m = s * (1.f/256.f);
        mu[row] = m;
        rs[row] = rsqrtf(s2 * (1.f/256.f) - m*m + LN_EPS);
    }
}

// ---------------- slots init + LN(slots) + kap/lam ----------------
__global__ __launch_bounds__(256) void k_prep_s(const void* __restrict__ qp,
    const float* __restrict__ lsw, const float* __restrict__ lsb,
    const float* __restrict__ u1, const float* __restrict__ u2, const float* __restrict__ c12,
    float* __restrict__ slots, u16* __restrict__ Acat, u16* __restrict__ s_b,
    float* __restrict__ kap, float* __restrict__ lam, const int* flagp) {
    int bf = *flagp;
    int m = blockIdx.x;
    int s_ = m & 7, d = threadIdx.x;
    float v = ld1(qp, (size_t)s_ * 256 + d, bf);
    slots[(size_t)m*256 + d]   = v;
    Acat[(size_t)m*512 + 256 + d] = f2bf(v);
    __shared__ float red[16];
    float su = warp_sum64(v), sq = warp_sum64(v*v);
    int wave = threadIdx.x >> 6, lane = threadIdx.x & 63;
    if (lane == 0) { red[wave] = su; red[4+wave] = sq; }
    __syncthreads();
    float S1 = red[0]+red[1]+red[2]+red[3], S2 = red[4]+red[5]+red[6]+red[7];
    float muv = S1*(1.f/256.f);
    float rsv = rsqrtf(S2*(1.f/256.f) - muv*muv + LN_EPS);
    float sn = (v - muv)*rsv*lsw[d] + lsb[d];
    s_b[(size_t)m*256 + d] = f2bf(sn);
    float ks = warp_sum64(sn * u1[d]), ls = warp_sum64(sn * u2[d]);
    if (lane == 0) { red[8+wave] = ks; red[12+wave] = ls; }
    __syncthreads();
    if (threadIdx.x == 0) {
        kap[m] = red[8]+red[9]+red[10]+red[11] + c12[0];
        lam[m] = red[12]+red[13]+red[14]+red[15] + c12[1];
    }
}

// ---------------- 64x64 GEMM: C[M,N] = A[M,K].W[N,K]^T + bias ----------------
template<bool OUT_BF16, bool RELU>
__global__ __launch_bounds__(256) void gemm64(
    const u16* __restrict__ A, const u16* __restrict__ W,
    const float* __restrict__ bias, void* __restrict__ outp, int Nn, int K) {
    int m0 = blockIdx.x * 64, n0 = blockIdx.y * 64;
    int tid = threadIdx.x;
    int wave = tid >> 6, lane = tid & 63, quad = lane >> 4, l15 = lane & 15;
    int wm = wave >> 1, wn = wave & 1;
    __shared__ __attribute__((aligned(16))) u16 A_s[64*40];
    __shared__ __attribute__((aligned(16))) u16 B_s[64*40];
    f32x4v acc[2][2];
#pragma unroll
    for (int i = 0; i < 2; i++)
#pragma unroll
        for (int j = 0; j < 2; j++) acc[i][j] = (f32x4v){0.f,0.f,0.f,0.f};
    int r0 = tid >> 2, seg = tid & 3;
    int nkc = K >> 5;
    for (int kc = 0; kc < nkc; ++kc) {
        s16x8 a0 = *(const s16x8*)(A + (size_t)(m0 + r0)*K + kc*32 + seg*8);
        s16x8 b0 = *(const s16x8*)(W + (size_t)(n0 + r0)*K + kc*32 + seg*8);
        __syncthreads();
        *(s16x8*)(A_s + r0*40 + seg*8) = a0;
        *(s16x8*)(B_s + r0*40 + seg*8) = b0;
        __syncthreads();
        s16x8 af[2], bfr[2];
#pragma unroll
        for (int t = 0; t < 2; t++) af[t]  = *(const s16x8*)(A_s + (wm*32 + t*16 + l15)*40 + quad*8);
#pragma unroll
        for (int t = 0; t < 2; t++) bfr[t] = *(const s16x8*)(B_s + (wn*32 + t*16 + l15)*40 + quad*8);
#pragma unroll
        for (int ti = 0; ti < 2; ti++)
#pragma unroll
            for (int tj = 0; tj < 2; tj++)
                acc[ti][tj] = __builtin_amdgcn_mfma_f32_16x16x32_bf16(af[ti], bfr[tj], acc[ti][tj], 0, 0, 0);
    }
#pragma unroll
    for (int tj = 0; tj < 2; tj++) {
        int colg = n0 + wn*32 + tj*16 + l15;
        float bv_ = bias ? bias[colg] : 0.f;
#pragma unroll
        for (int ti = 0; ti < 2; ti++) {
            int rowb = m0 + wm*32 + ti*16 + quad*4;
#pragma unroll
            for (int r = 0; r < 4; r++) {
                float v = acc[ti][tj][r] + bv_;
                if (RELU) v = fmaxf(v, 0.f);
                if (OUT_BF16) ((u16*)outp)[(size_t)(rowb + r)*Nn + colg] = f2bf(v);
                else          ((float*)outp)[(size_t)(rowb + r)*Nn + colg] = v;
            }
        }
    }
}

// ---------------- assemble Wbig [1024][512] and bbig ----------------
__global__ __launch_bounds__(256) void k_big(const u16* __restrict__ Wc2_b,
    const u16* __restrict__ whh_b, const float* __restrict__ bih_f,
    const float* __restrict__ bhh_f, const float* __restrict__ wibv,
    u16* __restrict__ Wbig, float* __restrict__ bbig) {
    int idx = blockIdx.x * 256 + threadIdx.x;
    int n = idx >> 9, k = idx & 511;
    u16 v;
    if (n < 512)      v = (k < 256) ? Wc2_b[(size_t)n*256 + k] : whh_b[(size_t)n*256 + (k-256)];
    else if (n < 768) v = (k < 256) ? Wc2_b[(size_t)n*256 + k] : (u16)0;
    else              v = (k < 256) ? (u16)0 : whh_b[(size_t)(n-256)*256 + (k-256)];
    Wbig[idx] = v;
    if (idx < 1024) {
        float bb;
        if (idx < 512)      bb = bih_f[idx] + wibv[idx] + bhh_f[idx];
        else if (idx < 768) bb = bih_f[idx] + wibv[idx];
        else                bb = bhh_f[idx-256];
        bbig[idx] = bb;
    }
}

// ---------------- fused attention: dots + softmax + Z/R/T partials (single x pass) ----------------
__global__ __launch_bounds__(256) void k_attn(
    const void* __restrict__ xraw, const u16* __restrict__ q2b,
    const float* __restrict__ kap, const float* __restrict__ lam,
    const float* __restrict__ mu, const float* __restrict__ rs,
    const int* __restrict__ flagp,
    float* __restrict__ Zp, float* __restrict__ Rp, float* __restrict__ Tp) {
    int bf = *flagp;
    int jcc = blockIdx.x;   // 0..31, each covers 128 j (2 sub-tiles of 64)
    int b   = blockIdx.y;   // 0..63
    int tid = threadIdx.x;
    int wave = tid >> 6, lane = tid & 63, quad = lane >> 4, l15 = lane & 15;
    __shared__ __attribute__((aligned(16))) u16 q_s[16*264];
    __shared__ __attribute__((aligned(16))) u16 a_s[16*72];
    __shared__ __attribute__((aligned(16))) u16 T_s[32*520];   // T[cb][j]: addr=cb*520 + j*8 (+t)
    __shared__ float kl_s[32];
    {   // stage q2 rows 0..7, zero rows 8..15
        int row = tid >> 5, seg = tid & 31;
        s16x8 qv = *(const s16x8*)(q2b + (size_t)(b*8 + row)*256 + seg*8);
        *(s16x8*)(q_s + row*264 + seg*8) = qv;
        s16x8 z = {0,0,0,0,0,0,0,0};
        *(s16x8*)(q_s + (8+row)*264 + seg*8) = z;
    }
    if (tid < 16) {
        kl_s[tid]      = (tid < 8) ? kap[b*8 + tid] : 0.f;
        kl_s[16 + tid] = (tid < 8) ? lam[b*8 + tid] : 0.f;
    }
    f32x4v accz[4];
#pragma unroll
    for (int t = 0; t < 4; t++) accz[t] = (f32x4v){0.f,0.f,0.f,0.f};
    float rtot[4] = {0.f,0.f,0.f,0.f}, ttot[4] = {0.f,0.f,0.f,0.f};

    for (int sub = 0; sub < 2; ++sub) {
        size_t jbase = (size_t)b*4096 + (size_t)(jcc*2 + sub)*64;
        __syncthreads();   // previous sub's readers done (also syncs q_s/kl_s on sub 0)
        // ---- stage x tile: 64 j x 256 c ----
#pragma unroll
        for (int it = 0; it < 8; ++it) {
            int j = it*8 + (tid >> 5);
            int cb = tid & 31;
            s16x8 val;
            if (bf) {
                val = *(const s16x8*)((const u16*)xraw + (jbase + j)*256 + cb*8);
            } else {
                const float4* sf = (const float4*)((const float*)xraw + (jbase + j)*256 + cb*8);
                float4 f0 = sf[0], f1 = sf[1];
                val = pack8(f0, f1);
            }
            *(s16x8*)(T_s + cb*520 + j*8) = val;
        }
        __syncthreads();
        // ---- dots: wave handles its 16-j slice ----
        f32x4v accd = (f32x4v){0.f,0.f,0.f,0.f};
        int jb16 = wave * 16;
#pragma unroll
        for (int kc = 0; kc < 8; ++kc) {
            s16x8 af = *(const s16x8*)(q_s + l15*264 + kc*32 + quad*8);
            s16x8 bv = *(const s16x8*)(T_s + (kc*4 + quad)*520 + (jb16 + l15)*8);
            accd = __builtin_amdgcn_mfma_f32_16x16x32_bf16(af, bv, accd, 0, 0, 0);
        }
        // ---- affine fixup + softmax over i (pairs lane<->lane^16) ----
        int jg = (int)jbase + jb16 + l15;
        float rsj = rs[jg], mrj = mu[jg] * rsj;
        float dv[4];
#pragma unroll
        for (int r = 0; r < 4; r++)
            dv[r] = SCALE*(rsj*accd[r] + mrj*kl_s[16 + quad*4 + r] + kl_s[quad*4 + r]);
        float mx = fmaxf(fmaxf(dv[0], dv[1]), fmaxf(dv[2], dv[3]));
        mx = fmaxf(mx, __shfl_xor(mx, 16));
        float ev[4];
        float sum = 0.f;
#pragma unroll
        for (int r = 0; r < 4; r++) { ev[r] = expf(dv[r] - mx); sum += ev[r]; }
        sum += __shfl_xor(sum, 16);
        float inv = 1.f / sum;
#pragma unroll
        for (int r = 0; r < 4; r++) {
            float a = ev[r]*inv + EPS;
            rtot[r] += a;
            ttot[r] += a * mrj;
            a_s[(quad*4 + r)*72 + jb16 + l15] = f2bf(a * rsj);
        }
        __syncthreads();   // a_s ready
        // ---- Z += a2 . x  (contract this sub's 64 j) ----
#pragma unroll
        for (int kc2 = 0; kc2 < 2; ++kc2) {
            s16x8 af2 = *(const s16x8*)(a_s + l15*72 + kc2*32 + quad*8);
#pragma unroll
            for (int ct = 0; ct < 4; ++ct) {
                int c = wave*64 + ct*16 + l15;
                int cb = c >> 3, e = c & 7;
                s16x8 bv;
#pragma unroll
                for (int t = 0; t < 8; t++)
                    bv[t] = (short)T_s[cb*520 + (kc2*32 + quad*8 + t)*8 + e];
                accz[ct] = __builtin_amdgcn_mfma_f32_16x16x32_bf16(af2, bv, accz[ct], 0, 0, 0);
            }
        }
    }
    // ---- write partials ----
    if (quad < 2) {
#pragma unroll
        for (int ct = 0; ct < 4; ++ct) {
            int c = wave*64 + ct*16 + l15;
#pragma unroll
            for (int r = 0; r < 4; r++)
                Zp[((size_t)(b*32 + jcc)*8 + quad*4 + r)*256 + c] = accz[ct][r];
        }
    }
#pragma unroll
    for (int r = 0; r < 4; r++) {
        rtot[r] += __shfl_xor(rtot[r], 1);
        rtot[r] += __shfl_xor(rtot[r], 2);
        rtot[r] += __shfl_xor(rtot[r], 4);
        rtot[r] += __shfl_xor(rtot[r], 8);
        ttot[r] += __shfl_xor(ttot[r], 1);
        ttot[r] += __shfl_xor(ttot[r], 2);
        ttot[r] += __shfl_xor(ttot[r], 4);
        ttot[r] += __shfl_xor(ttot[r], 8);
    }
    if (l15 == 0 && quad < 2) {
        int base = ((b*32 + jcc)*4 + wave)*8 + quad*4;
#pragma unroll
        for (int r = 0; r < 4; r++) { Rp[base + r] = rtot[r]; Tp[base + r] = ttot[r]; }
    }
}

// ---------------- reduce Z/R/T -> Ys (= updates-precursor / R) into A_cat cols 0..255 ----------------
__global__ __launch_bounds__(256) void k_reduce(const float* __restrict__ Zp,
    const float* __restrict__ Rp, const float* __restrict__ Tp,
    const float* __restrict__ liw, const float* __restrict__ lib,
    u16* __restrict__ Acat) {
    int m = blockIdx.x;   // b*8 + i
    int b = m >> 3, i = m & 7, d = threadIdx.x;
    float z = 0.f;
#pragma unroll
    for (int c = 0; c < 32; c++) z += Zp[((size_t)(b*32 + c)*8 + i)*256 + d];
    float rv = 0.f, tv = 0.f;
    if (d < 128) {
        rv = Rp[(size_t)(b*128 + d)*8 + i];
        tv = Tp[(size_t)(b*128 + d)*8 + i];
    }
    __shared__ float redR[4], redT[4];
    rv = warp_sum64(rv); tv = warp_sum64(tv);
    int wave = d >> 6, lane = d & 63;
    if (lane == 0) { redR[wave] = rv; redT[wave] = tv; }
    __syncthreads();
    float R = redR[0]+redR[1]+redR[2]+redR[3];
    float T = redT[0]+redT[1]+redT[2]+redT[3];
    float ys = (liw[d]*(z - T) + lib[d]*R) / R;
    Acat[(size_t)m*512 + d] = f2bf(ys);
}

// ---------------- GRU gates + h + LN_ff(h) ----------------
__global__ __launch_bounds__(256) void k_gates(const float* __restrict__ g,
    const float* __restrict__ slots, const float* __restrict__ lfw,
    const float* __restrict__ lfb, float* __restrict__ h, u16* __restrict__ hln_b) {
    int m = blockIdx.x, d = threadIdx.x;
    const float* gm = g + (size_t)m*1024;
    float r = sigf(gm[d]);
    float z = sigf(gm[256 + d]);
    float nn = tanhf(gm[512 + d] + r * gm[768 + d]);
    float hv = (1.f - z)*nn + z*slots[(size_t)m*256 + d];
    h[(size_t)m*256 + d] = hv;
    __shared__ float red[8];
    float su = warp_sum64(hv), sq = warp_sum64(hv*hv);
    int wave = threadIdx.x >> 6, lane = threadIdx.x & 63;
    if (lane == 0) { red[wave] = su; red[4+wave] = sq; }
    __syncthreads();
    float S1 = red[0]+red[1]+red[2]+red[3], S2 = red[4]+red[5]+red[6]+red[7];
    float muv = S1*(1.f/256.f);
    float rsv = rsqrtf(S2*(1.f/256.f) - muv*muv + LN_EPS);
    hln_b[(size_t)m*256 + d] = f2bf((hv - muv)*rsv*lfw[d] + lfb[d]);
}

// ---------------- residual + next LN(slots) + kap/lam ----------------
__global__ __launch_bounds__(256) void k_residual(const float* __restrict__ h,
    const float* __restrict__ ff2, const float* __restrict__ lsw,
    const float* __restrict__ lsb, const float* __restrict__ u1,
    const float* __restrict__ u2, const float* __restrict__ c12,
    float* __restrict__ slots, u16* __restrict__ Acat, u16* __restrict__ s_b,
    float* __restrict__ kap, float* __restrict__ lam) {
    int m = blockIdx.x, d = threadIdx.x;
    float sv = h[(size_t)m*256 + d] + ff2[(size_t)m*256 + d];
    slots[(size_t)m*256 + d] = sv;
    Acat[(size_t)m*512 + 256 + d] = f2bf(sv);
    __shared__ float red[16];
    float su = warp_sum64(sv), sq = warp_sum64(sv*sv);
    int wave = threadIdx.x >> 6, lane = threadIdx.x & 63;
    if (lane == 0) { red[wave] = su; red[4+wave] = sq; }
    __syncthreads();
    float S1 = red[0]+red[1]+red[2]+red[3], S2 = red[4]+red[5]+red[6]+red[7];
    float muv = S1*(1.f/256.f);
    float rsv = rsqrtf(S2*(1.f/256.f) - muv*muv + LN_EPS);
    float sn = (sv - muv)*rsv*lsw[d] + lsb[d];
    s_b[(size_t)m*256 + d] = f2bf(sn);
    float ks = warp_sum64(sn * u1[d]), ls = warp_sum64(sn * u2[d]);
    if (lane == 0) { red[8+wave] = ks; red[12+wave] = ls; }
    __syncthreads();
    if (threadIdx.x == 0) {
        kap[m] = red[8]+red[9]+red[10]+red[11] + c12[0];
        lam[m] = red[12]+red[13]+red[14]+red[15] + c12[1];
    }
}

// ---------------- final output ----------------
__global__ __launch_bounds__(256) void k_out(const float* __restrict__ slots,
                                             void* __restrict__ out, const int* flagp) {
    int bf = *flagp;
    int i = blockIdx.x * 256 + threadIdx.x;
    if (bf) ((u16*)out)[i] = f2bf(slots[i]);
    else    ((float*)out)[i] = slots[i];
}

extern "C" void kernel_launch(void* const* d_in, const int* in_sizes, int n_in,
                              void* d_out, int out_size, void* d_ws, size_t ws_size,
                              hipStream_t stream) {
    (void)in_sizes; (void)n_in; (void)out_size; (void)ws_size;
    const void* inputs    = d_in[0];
    const void* query_pos = d_in[1];
    const void* wq   = d_in[2];  const void* bq   = d_in[3];
    const void* wk   = d_in[4];  const void* bk   = d_in[5];
    const void* wv   = d_in[6];  const void* bv   = d_in[7];
    const void* w_ih = d_in[8];  const void* b_ih = d_in[9];
    const void* w_hh = d_in[10]; const void* b_hh = d_in[11];
    const void* w1   = d_in[12]; const void* b1   = d_in[13];
    const void* w2   = d_in[14]; const void* b2   = d_in[15];
    const void* ln_in_w = d_in[16]; const void* ln_in_b = d_in[17];
    const void* ln_s_w  = d_in[18]; const void* ln_s_b  = d_in[19];
    const void* ln_ff_w = d_in[20]; const void* ln_ff_b = d_in[21];

    char* w = (char*)d_ws;
    size_t off = 0;
    auto alloc = [&](size_t bytes) -> void* {
        void* p = w + off;
        off = (off + bytes + 255) & ~(size_t)255;
        return p;
    };
    float* Zp     = (float*)alloc(16777216);   // [64*32][8][256] f32
    float* gates  = (float*)alloc(2097152);    // [512][1024] f32
    u16*   Wbig_b = (u16*)alloc(1048576);      // [1024][512]
    u16*   Wc2_b  = (u16*)alloc(393216);       // [768][256]
    u16*   Wc_b   = (u16*)alloc(131072);       // [256][256]
    u16*   wqT_b  = (u16*)alloc(131072);
    u16*   wvT_b  = (u16*)alloc(131072);
    u16*   wk2_b  = (u16*)alloc(131072);
    u16*   wih_b  = (u16*)alloc(393216);
    u16*   whh_b  = (u16*)alloc(393216);
    u16*   w1_b   = (u16*)alloc(262144);
    u16*   w2_b   = (u16*)alloc(262144);
    float* mu     = (float*)alloc(1048576);
    float* rs     = (float*)alloc(1048576);
    float* slots  = (float*)alloc(524288);
    u16*   s_b    = (u16*)alloc(262144);
    u16*   Acat   = (u16*)alloc(524288);       // [512][512]: [Ys | slots]
    u16*   q2_b   = (u16*)alloc(262144);
    float* h      = (float*)alloc(524288);
    u16*   hln_b  = (u16*)alloc(262144);
    u16*   ff1_b  = (u16*)alloc(524288);
    float* ff2    = (float*)alloc(524288);
    float* Rp     = (float*)alloc(262144);
    float* Tp     = (float*)alloc(262144);
    float* bq_f   = (float*)alloc(1024);
    float* bk_f   = (float*)alloc(1024);
    float* bv_f   = (float*)alloc(1024);
    float* bih_f  = (float*)alloc(3072);
    float* bhh_f  = (float*)alloc(3072);
    float* b1_f   = (float*)alloc(2048);
    float* b2_f   = (float*)alloc(1024);
    float* liw_f  = (float*)alloc(1024);
    float* lib_f  = (float*)alloc(1024);
    float* lsw_f  = (float*)alloc(1024);
    float* lsb_f  = (float*)alloc(1024);
    float* lfw_f  = (float*)alloc(1024);
    float* lfb_f  = (float*)alloc(1024);
    float* m1p    = (float*)alloc(1024);
    float* m2p    = (float*)alloc(1024);
    float* u1     = (float*)alloc(1024);
    float* u2     = (float*)alloc(1024);
    float* bq2    = (float*)alloc(1024);
    float* wibv   = (float*)alloc(3072);
    float* bbig   = (float*)alloc(4096);
    float* c12    = (float*)alloc(256);
    float* kap    = (float*)alloc(2048);
    float* lam    = (float*)alloc(2048);
    int*   flag   = (int*)alloc(256);

    // ---- prep ----
    k_sniff<<<1, 64, 0, stream>>>(inputs, flag);
    k_prep_misc<<<18, 256, 0, stream>>>(bq, bk, bv, b_ih, b_hh, b1, b2,
                                        ln_in_w, ln_in_b, ln_s_w, ln_s_b, ln_ff_w, ln_ff_b,
                                        bq_f, bk_f, bv_f, bih_f, bhh_f, b1_f, b2_f,
                                        liw_f, lib_f, lsw_f, lsb_f, lfw_f, lfb_f, flag);
    k_stats<<<65536, 256, 0, stream>>>(inputs, mu, rs, flag);
    k_prep_w<<<3328, 256, 0, stream>>>(wq, wv, wk, w_ih, w_hh, w1, w2,
                                       wqT_b, wvT_b, wk2_b, wih_b, whh_b, w1_b, w2_b,
                                       liw_f, flag);
    k_prep_m<<<64, 256, 0, stream>>>(wk, liw_f, lib_f, bk_f, m1p, m2p, flag);
    k_prep_u<<<385, 256, 0, stream>>>(wq, wk, w_ih, m1p, m2p, bq_f, bv_f, liw_f,
                                      u1, u2, bq2, wibv, c12, flag);
    k_prep_s<<<512, 256, 0, stream>>>(query_pos, lsw_f, lsb_f, u1, u2, c12,
                                      slots, Acat, s_b, kap, lam, flag);
    gemm64<true, false><<<dim3(4, 4), 256, 0, stream>>>(wk2_b, wqT_b, nullptr, Wc_b, 256, 256);
    gemm64<true, false><<<dim3(12, 4), 256, 0, stream>>>(wih_b, wvT_b, nullptr, Wc2_b, 256, 256);
    k_big<<<2048, 256, 0, stream>>>(Wc2_b, whh_b, bih_f, bhh_f, wibv, Wbig_b, bbig);

    // ---- iterations ----
    for (int step = 0; step < 4; ++step) {
        gemm64<true, false><<<dim3(8, 4), 256, 0, stream>>>(s_b, Wc_b, bq2, q2_b, 256, 256);
        k_attn<<<dim3(32, 64), 256, 0, stream>>>(inputs, q2_b, kap, lam, mu, rs, flag, Zp, Rp, Tp);
        k_reduce<<<512, 256, 0, stream>>>(Zp, Rp, Tp, liw_f, lib_f, Acat);
        gemm64<false, false><<<dim3(8, 16), 256, 0, stream>>>(Acat, Wbig_b, bbig, gates, 1024, 512);
        k_gates<<<512, 256, 0, stream>>>(gates, slots, lfw_f, lfb_f, h, hln_b);
        gemm64<true, true ><<<dim3(8, 8), 256, 0, stream>>>(hln_b, w1_b, b1_f, ff1_b, 512, 256);
        gemm64<false, false><<<dim3(8, 4), 256, 0, stream>>>(ff1_b, w2_b, b2_f, ff2, 256, 512);
        k_residual<<<512, 256, 0, stream>>>(h, ff2, lsw_f, lsb_f, u1, u2, c12,
                                            slots, Acat, s_b, kap, lam);
    }
    k_out<<<512, 256, 0, stream>>>(slots, d_out, flag);
}